// Round 2
// baseline (210.161 us; speedup 1.0000x reference)
//
#include <hip/hip_runtime.h>
#include <hip/hip_bf16.h>

// Problem constants: N=1024, C=32, T=8, V=64, K=3, CT=256
// out[n][c][v][t] = sum_k sum_j W[k][c*8+t][j] * U_k[j][v] + bias2T[c*8+t][v]
// U_k[j][v] = sum_u x[n][j][u] * A[k][u][v]

typedef __attribute__((ext_vector_type(8))) short bf16x8;
typedef __attribute__((ext_vector_type(4))) float f32x4;

__device__ __forceinline__ short f2bf(float f) {
  union { float f; unsigned u; } c; c.f = f;
  unsigned r = c.u + 0x7FFFu + ((c.u >> 16) & 1u);   // RNE
  return (short)(r >> 16);
}

__device__ __forceinline__ unsigned pkbf(float a, float b) {
  float2 t; t.x = a; t.y = b;
  union { __hip_bfloat162 h; unsigned u; } c;
  c.h = __float22bfloat162_rn(t);   // v_cvt_pk_bf16_f32 on gfx950, RNE
  return c.u;
}

// ---------------- workspace layout (bytes) ----------------
// Wsw   : short[196608] @ 0        fragment-ordered W  (k,wv,mt,ks,lane,e)
// Asw   : short[12288]  @ 393216   fragment-ordered A^T (k,ks,nt,lane,e)
// biasCM: float[16384]  @ 417792   column-major bias: biasCM[w*256 + d]
#define ASW_OFF  393216
#define BIAS_OFF 417792

__global__ __launch_bounds__(256) void prep_kernel(
    const float* __restrict__ W, const float* __restrict__ b,
    const float* __restrict__ A, short* __restrict__ Wsw,
    short* __restrict__ Asw, float* __restrict__ biasCM) {
  int t = blockIdx.x * 256 + threadIdx.x;
  if (t < 196608) {
    // Wsw flat = ((((k*4+wv)*4+mt)*8+ks)*64 + lane)*8 + e
    int e = t & 7, l = (t >> 3) & 63, ks = (t >> 9) & 7, mt = (t >> 12) & 3,
        wv = (t >> 14) & 3, k = t >> 16;
    int d = wv * 64 + mt * 16 + (l & 15);
    int c = ks * 32 + (l >> 4) * 8 + e;
    Wsw[t] = f2bf(W[(k * 256 + d) * 256 + c]);
  } else if (t < 196608 + 12288) {
    // Asw flat = (((k*2+ks)*4+nt)*64 + lane)*8 + e ; value = A[k][v][w]
    int t2 = t - 196608;
    int e = t2 & 7, l = (t2 >> 3) & 63, nt = (t2 >> 9) & 3, ks = (t2 >> 11) & 1,
        k = t2 >> 12;
    int w = nt * 16 + (l & 15);
    int v = ks * 32 + (l >> 4) * 8 + e;
    Asw[t2] = f2bf(A[(k * 64 + v) * 64 + w]);
  } else {
    // biasCM[w*256 + d] = sum_k (sum_v A[k][v][w]) * b[k][d]
    // blocks here have uniform w = (t2>>8) across the block (tid = d)
    int t2 = t - 196608 - 12288;
    int w = t2 >> 8, d = t2 & 255;
    float s = 0.f;
    for (int k = 0; k < 3; ++k) {
      float cs = 0.f;
#pragma unroll
      for (int v = 0; v < 64; ++v) cs += A[(k * 64 + v) * 64 + w];
      s += cs * b[k * 256 + d];
    }
    biasCM[t2] = s;
  }
}

#define UT_STRIDE 264  // bf16 elems per Ut row (256 + 8 pad)

__global__ __launch_bounds__(256, 3) void gcn_main(
    const float* __restrict__ x, const short* __restrict__ Wsw,
    const short* __restrict__ Asw, const float* __restrict__ biasCM,
    float* __restrict__ out) {
  __shared__ short Ut[64 * UT_STRIDE];  // Ut[w][ct] = U[ct][w], 33792 B

  const int tid = threadIdx.x;
  const int wv = tid >> 6;
  const int lane = tid & 63;
  const int li = lane & 15;
  const int lq = lane >> 4;
  const int n = blockIdx.x;

  const float* xn = x + (size_t)n * 16384;
  float* outn = out + (size_t)n * 16384;

  // ---- acc2 init = bias (so epilogue is a pure store). biasCM is L2-hot.
  f32x4 acc2[4][4];
#pragma unroll
  for (int mt = 0; mt < 4; ++mt)
#pragma unroll
    for (int nt = 0; nt < 4; ++nt) {
      const float4 bb = *(const float4*)(biasCM + (nt * 16 + li) * 256 +
                                         64 * wv + mt * 16 + 4 * lq);
      acc2[mt][nt] = (f32x4){bb.x, bb.y, bb.z, bb.w};
    }

  // ---- stage-1 A-operand: wave's 64x64 block of Xn, registers, k-invariant
  bf16x8 xf[2][4];
#pragma unroll
  for (int ks = 0; ks < 2; ++ks)
#pragma unroll
    for (int mt = 0; mt < 4; ++mt) {
      const float4* p =
          (const float4*)(xn + (64 * wv + mt * 16 + li) * 64 + ks * 32 + lq * 8);
      float4 f0 = p[0], f1 = p[1];
      union { bf16x8 v; unsigned u[4]; } t;
      t.u[0] = pkbf(f0.x, f0.y); t.u[1] = pkbf(f0.z, f0.w);
      t.u[2] = pkbf(f1.x, f1.y); t.u[3] = pkbf(f1.z, f1.w);
      xf[ks][mt] = t.v;
    }

#pragma unroll
  for (int k = 0; k < 3; ++k) {
    const short* AswK = Asw + k * 4096;

    // ---------- stage 1 in two mt-halves (acc1 capped at 8 frags = 32 regs)
#pragma unroll
    for (int h = 0; h < 2; ++h) {
      f32x4 acc1[2][4];
#pragma unroll
      for (int m2 = 0; m2 < 2; ++m2)
#pragma unroll
        for (int nt = 0; nt < 4; ++nt)
          acc1[m2][nt] = (f32x4){0.f, 0.f, 0.f, 0.f};

#pragma unroll
      for (int ks = 0; ks < 2; ++ks) {
        bf16x8 bfr[4];
#pragma unroll
        for (int nt = 0; nt < 4; ++nt)
          bfr[nt] = *(const bf16x8*)(AswK + ((ks * 4 + nt) * 64 + lane) * 8);
#pragma unroll
        for (int m2 = 0; m2 < 2; ++m2)
#pragma unroll
          for (int nt = 0; nt < 4; ++nt)
            acc1[m2][nt] = __builtin_amdgcn_mfma_f32_16x16x32_bf16(
                xf[ks][2 * h + m2], bfr[nt], acc1[m2][nt], 0, 0, 0);
      }

      // write this half's U_k rows to Ut (transposed), packed cvt + b64 write
      // (safe: previous stage-2 readers drained by the sync at end of k-1)
#pragma unroll
      for (int m2 = 0; m2 < 2; ++m2)
#pragma unroll
        for (int nt = 0; nt < 4; ++nt) {
          int w = nt * 16 + li;
          int ct = 64 * wv + (2 * h + m2) * 16 + 4 * lq;
          union { unsigned u[2]; unsigned long long ull; } p;
          p.u[0] = pkbf(acc1[m2][nt][0], acc1[m2][nt][1]);
          p.u[1] = pkbf(acc1[m2][nt][2], acc1[m2][nt][3]);
          *(unsigned long long*)(&Ut[w * UT_STRIDE + ct]) = p.ull;
        }
    }

    __syncthreads();  // Ut ready for all waves

    // ---------- stage 2: acc2 += W_k[rows 64wv..] @ U_k
    const short* WswK = Wsw + (k * 4 + wv) * 16384;
#pragma unroll
    for (int ks = 0; ks < 8; ++ks) {
      bf16x8 aw[4], bu[4];
#pragma unroll
      for (int mt = 0; mt < 4; ++mt)
        aw[mt] = *(const bf16x8*)(WswK + ((mt * 8 + ks) * 64 + lane) * 8);
#pragma unroll
      for (int nt = 0; nt < 4; ++nt)
        bu[nt] = *(const bf16x8*)(&Ut[(nt * 16 + li) * UT_STRIDE + ks * 32 + lq * 8]);
#pragma unroll
      for (int mt = 0; mt < 4; ++mt)
#pragma unroll
        for (int nt = 0; nt < 4; ++nt)
          acc2[mt][nt] = __builtin_amdgcn_mfma_f32_16x16x32_bf16(
              aw[mt], bu[nt], acc2[mt][nt], 0, 0, 0);
    }

    if (k < 2) __syncthreads();  // readers done before next k's Ut writes
  }

  // ---------- epilogue: direct float4 stores from C-layout (bias already in)
  // frag (mt,nt), lane (li,lq): d = 64wv+16mt+4lq+r -> c = 8wv+2mt+(lq>>1),
  // t = 4*(lq&1)+r, w = 16nt+li.  One float4 per frag.
#pragma unroll
  for (int mt = 0; mt < 4; ++mt)
#pragma unroll
    for (int nt = 0; nt < 4; ++nt) {
      float4 vv;
      vv.x = acc2[mt][nt][0];
      vv.y = acc2[mt][nt][1];
      vv.z = acc2[mt][nt][2];
      vv.w = acc2[mt][nt][3];
      *(float4*)(outn + (8 * wv + 2 * mt + (lq >> 1)) * 512 +
                 (nt * 16 + li) * 8 + 4 * (lq & 1)) = vv;
    }
}

extern "C" void kernel_launch(void* const* d_in, const int* in_sizes, int n_in,
                              void* d_out, int out_size, void* d_ws, size_t ws_size,
                              hipStream_t stream) {
  (void)in_sizes; (void)n_in; (void)out_size; (void)ws_size;
  const float* x = (const float*)d_in[0];
  const float* W = (const float*)d_in[1];
  const float* b = (const float*)d_in[2];
  const float* A = (const float*)d_in[3];
  float* out = (float*)d_out;

  short* Wsw = (short*)d_ws;
  short* Asw = (short*)((char*)d_ws + ASW_OFF);
  float* biasCM = (float*)((char*)d_ws + BIAS_OFF);

  // prep: 196608 (W) + 12288 (A) + 16384 (bias) = 225280 threads = 880 blocks
  prep_kernel<<<880, 256, 0, stream>>>(W, b, A, Wsw, Asw, biasCM);
  gcn_main<<<1024, 256, 0, stream>>>(x, Wsw, Asw, biasCM, out);
}

// Round 3
// 157.451 us; speedup vs baseline: 1.3348x; 1.3348x over previous
//
#include <hip/hip_runtime.h>
#include <hip/hip_bf16.h>

// Problem constants: N=1024, C=32, T=8, V=64, K=3, CT=256
// out[n][c][v][t] = sum_k sum_j W[k][c*8+t][j] * U_k[j][v] + bias2T[c*8+t][v]
// U_k[j][v] = sum_u x[n][j][u] * A[k][u][v]
//
// R3: 512-thread blocks (8 waves x 32 rows each) to halve per-wave register
// footprint (~108 VGPR incl accumulators) -> 2 blocks/CU, 16 waves/CU.
// R2 lesson: never cap regs below honest liveness (spill = 2x regression).

typedef __attribute__((ext_vector_type(8))) short bf16x8;
typedef __attribute__((ext_vector_type(4))) float f32x4;

__device__ __forceinline__ short f2bf(float f) {
  union { float f; unsigned u; } c; c.f = f;
  unsigned r = c.u + 0x7FFFu + ((c.u >> 16) & 1u);   // RNE
  return (short)(r >> 16);
}

__device__ __forceinline__ unsigned pkbf(float a, float b) {
  float2 t; t.x = a; t.y = b;
  union { __hip_bfloat162 h; unsigned u; } c;
  c.h = __float22bfloat162_rn(t);   // v_cvt_pk_bf16_f32, RNE
  return c.u;
}

// ---------------- workspace layout (bytes) ----------------
// Wsw   : short[196608] @ 0        fragment-ordered W  (k,wv8,mt,ks,lane,e)
// Asw   : short[12288]  @ 393216   fragment-ordered A^T (k,ks,nt,lane,e)
// biasCM: float[16384]  @ 417792   column-major bias: biasCM[w*256 + d]
#define ASW_OFF  393216
#define BIAS_OFF 417792

__global__ __launch_bounds__(256) void prep_kernel(
    const float* __restrict__ W, const float* __restrict__ b,
    const float* __restrict__ A, short* __restrict__ Wsw,
    short* __restrict__ Asw, float* __restrict__ biasCM) {
  int t = blockIdx.x * 256 + threadIdx.x;
  if (t < 196608) {
    // Wsw flat = ((((k*8+wv)*2+mt)*8+ks)*64 + lane)*8 + e
    int e = t & 7, l = (t >> 3) & 63, ks = (t >> 9) & 7, mt = (t >> 12) & 1,
        wv = (t >> 13) & 7, k = t >> 16;
    int d = 32 * wv + 16 * mt + (l & 15);
    int c = 32 * ks + 8 * (l >> 4) + e;
    Wsw[t] = f2bf(W[(k * 256 + d) * 256 + c]);
  } else if (t < 196608 + 12288) {
    // Asw flat = (((k*2+ks)*4+nt)*64 + lane)*8 + e ; value = A[k][v][w]
    int t2 = t - 196608;
    int e = t2 & 7, l = (t2 >> 3) & 63, nt = (t2 >> 9) & 3, ks = (t2 >> 11) & 1,
        k = t2 >> 12;
    int w = nt * 16 + (l & 15);
    int v = ks * 32 + (l >> 4) * 8 + e;
    Asw[t2] = f2bf(A[(k * 64 + v) * 64 + w]);
  } else {
    // biasCM[w*256 + d] = sum_k (sum_v A[k][v][w]) * b[k][d]
    int t2 = t - 196608 - 12288;
    int w = t2 >> 8, d = t2 & 255;
    float s = 0.f;
    for (int k = 0; k < 3; ++k) {
      float cs = 0.f;
#pragma unroll
      for (int v = 0; v < 64; ++v) cs += A[(k * 64 + v) * 64 + w];
      s += cs * b[k * 256 + d];
    }
    biasCM[t2] = s;
  }
}

#define UT_STRIDE 264  // bf16 elems per Ut row (256 + 8 pad)

__global__ __launch_bounds__(512, 4) void gcn_main(
    const float* __restrict__ x, const short* __restrict__ Wsw,
    const short* __restrict__ Asw, const float* __restrict__ biasCM,
    float* __restrict__ out) {
  __shared__ short Ut[64 * UT_STRIDE];  // Ut[w][ct] = U[ct][w], 33792 B

  const int tid = threadIdx.x;
  const int wv = tid >> 6;        // wave 0..7, owns rows [32wv, 32wv+32)
  const int lane = tid & 63;
  const int li = lane & 15;
  const int lq = lane >> 4;
  const int n = blockIdx.x;

  const float* xn = x + (size_t)n * 16384;
  float* outn = out + (size_t)n * 16384;

  // ---- acc2 init = bias (epilogue becomes a pure store); biasCM is L2-hot
  f32x4 acc2[2][4];
#pragma unroll
  for (int mt = 0; mt < 2; ++mt)
#pragma unroll
    for (int nt = 0; nt < 4; ++nt) {
      const float4 bb = *(const float4*)(biasCM + (nt * 16 + li) * 256 +
                                         32 * wv + 16 * mt + 4 * lq);
      acc2[mt][nt] = (f32x4){bb.x, bb.y, bb.z, bb.w};
    }

  // ---- stage-1 A-operand: wave's 32x64 block of Xn, registers, k-invariant
  bf16x8 xf[2][2];
#pragma unroll
  for (int ks = 0; ks < 2; ++ks)
#pragma unroll
    for (int mt = 0; mt < 2; ++mt) {
      const float4* p =
          (const float4*)(xn + (32 * wv + 16 * mt + li) * 64 + 32 * ks + 8 * lq);
      float4 f0 = p[0], f1 = p[1];
      union { bf16x8 v; unsigned u[4]; } t;
      t.u[0] = pkbf(f0.x, f0.y); t.u[1] = pkbf(f0.z, f0.w);
      t.u[2] = pkbf(f1.x, f1.y); t.u[3] = pkbf(f1.z, f1.w);
      xf[ks][mt] = t.v;
    }

#pragma unroll
  for (int k = 0; k < 3; ++k) {
    const short* AswK = Asw + k * 4096;

    // ---------- stage 1: U_k rows [32wv, 32wv+32), all 64 cols ----------
    f32x4 acc1[2][4];
#pragma unroll
    for (int mt = 0; mt < 2; ++mt)
#pragma unroll
      for (int nt = 0; nt < 4; ++nt)
        acc1[mt][nt] = (f32x4){0.f, 0.f, 0.f, 0.f};

#pragma unroll
    for (int ks = 0; ks < 2; ++ks) {
      bf16x8 bfr[4];
#pragma unroll
      for (int nt = 0; nt < 4; ++nt)
        bfr[nt] = *(const bf16x8*)(AswK + ((ks * 4 + nt) * 64 + lane) * 8);
#pragma unroll
      for (int mt = 0; mt < 2; ++mt)
#pragma unroll
        for (int nt = 0; nt < 4; ++nt)
          acc1[mt][nt] = __builtin_amdgcn_mfma_f32_16x16x32_bf16(
              xf[ks][mt], bfr[nt], acc1[mt][nt], 0, 0, 0);
    }

    // write U_k -> Ut transposed (prev readers drained by end-of-k barrier)
#pragma unroll
    for (int mt = 0; mt < 2; ++mt)
#pragma unroll
      for (int nt = 0; nt < 4; ++nt) {
        int w = nt * 16 + li;
        int ct = 32 * wv + 16 * mt + 4 * lq;
        union { unsigned u[2]; unsigned long long ull; } p;
        p.u[0] = pkbf(acc1[mt][nt][0], acc1[mt][nt][1]);
        p.u[1] = pkbf(acc1[mt][nt][2], acc1[mt][nt][3]);
        *(unsigned long long*)(&Ut[w * UT_STRIDE + ct]) = p.ull;
      }

    __syncthreads();  // Ut ready for all waves

    // ---------- stage 2: acc2 += W_k[rows 32wv..] @ U_k ----------
    const short* WswK = Wsw + (k * 8 + wv) * 8192;
#pragma unroll
    for (int ks = 0; ks < 8; ++ks) {
      bf16x8 aw[2], bu[4];
#pragma unroll
      for (int mt = 0; mt < 2; ++mt)
        aw[mt] = *(const bf16x8*)(WswK + ((mt * 8 + ks) * 64 + lane) * 8);
#pragma unroll
      for (int nt = 0; nt < 4; ++nt)
        bu[nt] = *(const bf16x8*)(&Ut[(nt * 16 + li) * UT_STRIDE + 32 * ks + 8 * lq]);
#pragma unroll
      for (int mt = 0; mt < 2; ++mt)
#pragma unroll
        for (int nt = 0; nt < 4; ++nt)
          acc2[mt][nt] = __builtin_amdgcn_mfma_f32_16x16x32_bf16(
              aw[mt], bu[nt], acc2[mt][nt], 0, 0, 0);
    }

    if (k < 2) __syncthreads();  // readers done before next k's Ut writes
  }

  // ---------- epilogue: direct float4 stores from C-layout ----------
  // d = 32wv+16mt+4lq+r -> c = 4wv+2mt+(lq>>1), t = 4(lq&1)+r, w = 16nt+li.
  // Per store inst: lanes cover 2 contiguous 512B spans -> well coalesced.
#pragma unroll
  for (int mt = 0; mt < 2; ++mt)
#pragma unroll
    for (int nt = 0; nt < 4; ++nt) {
      float4 vv;
      vv.x = acc2[mt][nt][0];
      vv.y = acc2[mt][nt][1];
      vv.z = acc2[mt][nt][2];
      vv.w = acc2[mt][nt][3];
      *(float4*)(outn + (4 * wv + 2 * mt + (lq >> 1)) * 512 +
                 (nt * 16 + li) * 8 + 4 * (lq & 1)) = vv;
    }
}

extern "C" void kernel_launch(void* const* d_in, const int* in_sizes, int n_in,
                              void* d_out, int out_size, void* d_ws, size_t ws_size,
                              hipStream_t stream) {
  (void)in_sizes; (void)n_in; (void)out_size; (void)ws_size;
  const float* x = (const float*)d_in[0];
  const float* W = (const float*)d_in[1];
  const float* b = (const float*)d_in[2];
  const float* A = (const float*)d_in[3];
  float* out = (float*)d_out;

  short* Wsw = (short*)d_ws;
  short* Asw = (short*)((char*)d_ws + ASW_OFF);
  float* biasCM = (float*)((char*)d_ws + BIAS_OFF);

  // prep: 196608 (W) + 12288 (A) + 16384 (bias) = 225280 threads = 880 blocks
  prep_kernel<<<880, 256, 0, stream>>>(W, b, A, Wsw, Asw, biasCM);
  gcn_main<<<1024, 512, 0, stream>>>(x, Wsw, Asw, biasCM, out);
}